// Round 13
// baseline (538.439 us; speedup 1.0000x reference)
//
#include <hip/hip_runtime.h>
#include <hip/hip_bf16.h>

// Causal linear attention (ELU+1), chunked, bf16 MFMA formulation — now 2 passes.
// B=4, T=8192, H=16, D=64, fp32 in/out.
// ws: 4096 records (bh*NCH+c) of REC=4160 fp32: S^T[e][d] (4096) then z[d] (64).
// ws requirement: 68.2 MB (unchanged).
//
// R13 changes vs R7 (measured 507 us; R7's swizzle cut bank-conflicts 37% but
// was time-neutral -> conflicts not on critical path):
//  - k_segscan REMOVED. Its 65KB-stride access pattern is a likely HBM
//    channel-aliasing victim (explains the stable ~370us non-k_output
//    remainder across four pass-1 designs). k_output now computes the
//    segment-prefix base inline: block for segment g sums total-slots of
//    segments g' < g (<=15 records, L2-hot, same fp32 order as segscan ->
//    bit-identical). chunkscan unchanged; ws is read-only in pass 2.
//  - 2 kernel launches instead of 3.

#define EPS_ 1e-6f

constexpr int Bc  = 4;
constexpr int Tc  = 8192;
constexpr int Hc  = 16;
constexpr int Dc  = 64;
constexpr int CH  = 128;          // chunk length
constexpr int NCH = Tc / CH;      // 64
constexpr int BHc = Bc * Hc;      // 64
constexpr int REC = Dc * Dc + Dc; // 4160
constexpr int SEG = 16;           // segments per bh
constexpr int CPS = NCH / SEG;    // 4 chunks per segment

typedef short  bf16x8 __attribute__((ext_vector_type(8)));  // 8 bf16 (4 VGPRs)
typedef float  f32x4  __attribute__((ext_vector_type(4)));

__device__ __forceinline__ float phi_f(float x) {
    return x > 0.f ? x + 1.f : __expf(x);   // elu(x)+1
}
__device__ __forceinline__ unsigned short f2b(float x) {
    __hip_bfloat16 b = __float2bfloat16(x);          // round-to-nearest-even
    return __builtin_bit_cast(unsigned short, b);
}
__device__ __forceinline__ float b2f(unsigned short u) {
    return __uint_as_float(((unsigned)u) << 16);     // exact
}
// Swizzled ushort index into a [64][136] tile: XOR the 16B-block bits of the
// column with (row>>2)&7.  Writes (ushort4, col%4==0) stay 8B-aligned inside a
// 16B block; reads (bf16x8, col%8==0) stay 16B-aligned.
__device__ __forceinline__ int swz(int row, int colu) {
    return row * 136 + (colu ^ (((row >> 2) & 7) << 3));
}

// ---- pass 1: segmented scan.  Block (bh,seg) walks its CPS chunks serially,
//      acc registers carry running S^T; writes EXCLUSIVE local prefix records;
//      segment total goes into record slot of chunk seg*CPS (local prefix there
//      is identically 0 and is reconstructed in pass 2).
__global__ __launch_bounds__(256, 4) void k_chunkscan(const float* __restrict__ kin,
                                                      const float* __restrict__ vin,
                                                      float* __restrict__ ws) {
    const int blk = blockIdx.x;              // bh*SEG + seg
    const int bh  = blk >> 4, seg = blk & (SEG - 1);
    const int b   = bh >> 4,  h   = bh & 15;
    const int tid = threadIdx.x;
    const int w = tid >> 6, lane = tid & 63;
    const int l15 = lane & 15, quad = lane >> 4;

    __shared__ unsigned short ktr[64 * 136];  // phiK^T [d][s] (swizzled)
    __shared__ unsigned short vtr[64 * 136];  // V^T    [e][s] (swizzled)
    __shared__ float zred[16][68];            // z partials [rowgroup][d] (padded)

    const int c0 = (tid & 15) << 2;          // d/e col group 0..60
    const int rl = (tid >> 4) << 2;          // row group 0..60

    f32x4 acc[4];
    #pragma unroll
    for (int nt = 0; nt < 4; nt++) acc[nt] = (f32x4){0.f, 0.f, 0.f, 0.f};
    float zrun = 0.f;                        // running z[d=tid] (tid<64)

    unsigned short hk[2][4][4], hv[2][4][4];
    float zp[4];

    auto load_chunk = [&](int c) {
        zp[0] = zp[1] = zp[2] = zp[3] = 0.f;
        #pragma unroll
        for (int sh = 0; sh < 2; ++sh) {
            const int r0 = rl + sh * 64;
            #pragma unroll
            for (int jj = 0; jj < 4; ++jj) {
                const size_t g = ((((size_t)b * Tc) + (c * CH + r0 + jj)) * Hc + h) * Dc + c0;
                const float4 kk = *(const float4*)(kin + g);
                const float4 vv = *(const float4*)(vin + g);
                hk[sh][jj][0] = f2b(phi_f(kk.x)); hk[sh][jj][1] = f2b(phi_f(kk.y));
                hk[sh][jj][2] = f2b(phi_f(kk.z)); hk[sh][jj][3] = f2b(phi_f(kk.w));
                hv[sh][jj][0] = f2b(vv.x); hv[sh][jj][1] = f2b(vv.y);
                hv[sh][jj][2] = f2b(vv.z); hv[sh][jj][3] = f2b(vv.w);
                #pragma unroll
                for (int j = 0; j < 4; ++j) zp[j] += b2f(hk[sh][jj][j]);
            }
        }
    };

    load_chunk(seg * CPS);                   // prologue

    for (int i = 0; i < CPS; ++i) {
        const int c = seg * CPS + i;
        float* rec = ws + (size_t)(bh * NCH + c) * REC;

        __syncthreads();   // previous chunk's LDS consumers done

        // LDS transpose stores (swizzled, conflict-free)
        #pragma unroll
        for (int sh = 0; sh < 2; ++sh) {
            const int r0 = rl + sh * 64;
            #pragma unroll
            for (int j = 0; j < 4; ++j) {
                *(ushort4*)&ktr[swz(c0 + j, r0)] =
                    make_ushort4(hk[sh][0][j], hk[sh][1][j], hk[sh][2][j], hk[sh][3][j]);
                *(ushort4*)&vtr[swz(c0 + j, r0)] =
                    make_ushort4(hv[sh][0][j], hv[sh][1][j], hv[sh][2][j], hv[sh][3][j]);
            }
        }
        #pragma unroll
        for (int j = 0; j < 4; ++j) zred[tid >> 4][c0 + j] = zp[j];

        // exclusive S record for this chunk (register data, overlaps LDS writes)
        if (i > 0) {
            #pragma unroll
            for (int nt = 0; nt < 4; nt++)
                #pragma unroll
                for (int r = 0; r < 4; r++)
                    rec[(16 * w + quad * 4 + r) * 64 + 16 * nt + l15] = acc[nt][r];
        }
        __syncthreads();   // ktr/vtr/zred visible

        float zs = 0.f;
        if (tid < 64) {
            if (i > 0) rec[4096 + tid] = zrun;      // exclusive z
            #pragma unroll
            for (int g = 0; g < 16; g++) zs += zred[g][tid];
        }

        // prefetch next chunk: loads + phi/f2b overlap the MFMA below
        if (i + 1 < CPS) load_chunk(c + 1);

        // S^T accumulate: acc[e][d] += V^T[e][s] * phiK[s][d]
        #pragma unroll
        for (int ks = 0; ks < 4; ks++) {
            bf16x8 a = *(const bf16x8*)&vtr[swz(16 * w + l15, quad * 8 + ks * 32)];
            #pragma unroll
            for (int nt = 0; nt < 4; nt++) {
                bf16x8 bb = *(const bf16x8*)&ktr[swz(16 * nt + l15, quad * 8 + ks * 32)];
                acc[nt] = __builtin_amdgcn_mfma_f32_16x16x32_bf16(a, bb, acc[nt], 0, 0, 0);
            }
        }
        if (tid < 64) zrun += zs;
    }

    // segment totals -> first-chunk record slot (consumed in-place by pass 2)
    {
        float* rec0 = ws + (size_t)(bh * NCH + seg * CPS) * REC;
        #pragma unroll
        for (int nt = 0; nt < 4; nt++)
            #pragma unroll
            for (int r = 0; r < 4; r++)
                rec0[(16 * w + quad * 4 + r) * 64 + 16 * nt + l15] = acc[nt][r];
        if (tid < 64) rec0[4096 + tid] = zrun;
    }
}

// ---------------- pass 2: outputs, one 512-thread block per FULL chunk ------------
__global__ __launch_bounds__(512, 4) void k_output(const float* __restrict__ qin,
                                                   const float* __restrict__ kin,
                                                   const float* __restrict__ vin,
                                                   const float* __restrict__ ws,
                                                   float* __restrict__ outp) {
    const int chunk = blockIdx.x;                // bh*NCH + c
    const int bh = chunk >> 6, c = chunk & (NCH - 1);
    const int b = bh >> 4, h = bh & 15;
    const int t0 = c * CH;
    const int tid = threadIdx.x;
    const int w = tid >> 6, lane = tid & 63;
    const int l15 = lane & 15, quad = lane >> 4;

    __shared__ unsigned short qb[128][72];  // phiQ [t][d]; cols reused as W[t][64+s']
    __shared__ unsigned short kb[128][72];  // phiK [s][d]; reused as W[t][s<64]
    __shared__ unsigned short sb[64][72];   // S^T[e][d] (prefixed, bf16)
    __shared__ unsigned short vb[64 * 136]; // V^T [e][s], s=0..127 (swizzled)
    __shared__ float zsh[64];
    __shared__ float den[128];

    // ---- stage phi(q), phi(k) natural (128 rows, 512 threads: one row each 1/4) --
    {
        const int row = tid >> 2, cb = (tid & 3) << 4;
        const size_t g = ((((size_t)b * Tc) + (t0 + row)) * Hc + h) * Dc + cb;
        const float4* qp = (const float4*)(qin + g);
        const float4* kp = (const float4*)(kin + g);
        #pragma unroll
        for (int i = 0; i < 4; i++) {
            float4 qq = qp[i];
            float4 kk = kp[i];
            *(ushort4*)&qb[row][cb + 4 * i] =
                make_ushort4(f2b(phi_f(qq.x)), f2b(phi_f(qq.y)), f2b(phi_f(qq.z)), f2b(phi_f(qq.w)));
            *(ushort4*)&kb[row][cb + 4 * i] =
                make_ushort4(f2b(phi_f(kk.x)), f2b(phi_f(kk.y)), f2b(phi_f(kk.z)), f2b(phi_f(kk.w)));
        }
    }
    // ---- stage V^T via in-register 4x4 transpose (swizzled stores) --------------
    {
        const int c0 = (tid & 15) << 2;          // e-col group 0..60
        const int r0 = (tid >> 4) << 2;          // s-row group 0..124
        unsigned short hv[4][4];
        #pragma unroll
        for (int jj = 0; jj < 4; ++jj) {
            const size_t g = ((((size_t)b * Tc) + (t0 + r0 + jj)) * Hc + h) * Dc + c0;
            const float4 vv = *(const float4*)(vin + g);
            hv[jj][0] = f2b(vv.x); hv[jj][1] = f2b(vv.y);
            hv[jj][2] = f2b(vv.z); hv[jj][3] = f2b(vv.w);
        }
        #pragma unroll
        for (int j = 0; j < 4; ++j)
            *(ushort4*)&vb[swz(c0 + j, r0)] = make_ushort4(hv[0][j], hv[1][j], hv[2][j], hv[3][j]);
    }
    // ---- stage (local prefix + inline segment-prefix base) -> sb, z -> zsh ------
    // Segment g = c/CPS.  base[e] = sum_{g'<g} total_g'[e], summed in segment
    // order (bit-identical to the old k_segscan prefix).  Total-slots are the
    // records of chunks g'*CPS, untouched since k_chunkscan.  L2-hot: each bh's
    // 16 total-slots (266 KB) are read by its 64 blocks.
    {
        const float* rec = ws + (size_t)chunk * REC;
        const float* tot0 = ws + (size_t)(bh * NCH) * REC;   // segment-total slots base
        const int gseg = c >> 2;                             // CPS = 4
        const bool cz = ((c & (CPS - 1)) == 0);              // this record IS a total slot
        #pragma unroll
        for (int i = 0; i < 2; i++) {
            const int idx = tid + i * 512;       // float4 index, 0..1023
            float4 sv = ((const float4*)rec)[idx];
            float4 bv = make_float4(0.f, 0.f, 0.f, 0.f);
            for (int gp = 0; gp < gseg; ++gp) {
                const float4 tv = ((const float4*)(tot0 + (size_t)(gp * CPS) * REC))[idx];
                bv.x += tv.x; bv.y += tv.y; bv.z += tv.z; bv.w += tv.w;
            }
            float4 t;
            if (cz) t = bv;
            else { t.x = sv.x + bv.x; t.y = sv.y + bv.y; t.z = sv.z + bv.z; t.w = sv.w + bv.w; }
            const int flat = idx * 4, e = flat >> 6, d = flat & 63;
            *(ushort4*)&sb[e][d] = make_ushort4(f2b(t.x), f2b(t.y), f2b(t.z), f2b(t.w));
        }
        if (tid < 16) {
            float4 zv = ((const float4*)(rec + 4096))[tid];
            float4 bz = make_float4(0.f, 0.f, 0.f, 0.f);
            for (int gp = 0; gp < gseg; ++gp) {
                const float4 tv = ((const float4*)(tot0 + (size_t)(gp * CPS) * REC + 4096))[tid];
                bz.x += tv.x; bz.y += tv.y; bz.z += tv.z; bz.w += tv.w;
            }
            float4 t;
            if (cz) t = bz;
            else { t.x = zv.x + bz.x; t.y = zv.y + bz.y; t.z = zv.z + bz.z; t.w = zv.w + bz.w; }
            zsh[tid * 4 + 0] = t.x; zsh[tid * 4 + 1] = t.y;
            zsh[tid * 4 + 2] = t.z; zsh[tid * 4 + 3] = t.w;
        }
    }
    __syncthreads();

    // den0 = eps + phiQ[t] . z
    if (tid < 128) {
        float s = 0.f;
        #pragma unroll
        for (int j = 0; j < 8; j++) {
            bf16x8 qv = *(const bf16x8*)&qb[tid][j * 8];
            #pragma unroll
            for (int u = 0; u < 8; u++) s += b2f((unsigned short)qv[u]) * zsh[j * 8 + u];
        }
        den[tid] = s + EPS_;
    }

    // GEMM1: acc[t][e] = phiQ[t][d] * S[d][e]   (B from S^T rows)
    f32x4 acc[4];
    #pragma unroll
    for (int nt = 0; nt < 4; nt++) acc[nt] = (f32x4){0.f, 0.f, 0.f, 0.f};
    #pragma unroll
    for (int ks = 0; ks < 2; ks++) {
        bf16x8 a = *(const bf16x8*)&qb[16 * w + l15][quad * 8 + ks * 32];
        #pragma unroll
        for (int nt = 0; nt < 4; nt++) {
            bf16x8 bb = *(const bf16x8*)&sb[16 * nt + l15][quad * 8 + ks * 32];
            acc[nt] = __builtin_amdgcn_mfma_f32_16x16x32_bf16(a, bb, acc[nt], 0, 0, 0);
        }
    }

    // GEMM2: W[t][s] = phiQ[t][d] * phiK[s][d].  Waves 0-3 (t<64) skip s>=64
    // (fully masked).  wt[nt] covers s = 16*nt + l15.
    f32x4 wt[8];
    #pragma unroll
    for (int nt = 0; nt < 8; nt++) wt[nt] = (f32x4){0.f, 0.f, 0.f, 0.f};
    #pragma unroll
    for (int ks = 0; ks < 2; ks++) {
        bf16x8 a = *(const bf16x8*)&qb[16 * w + l15][quad * 8 + ks * 32];
        #pragma unroll
        for (int nt = 0; nt < 4; nt++) {
            bf16x8 bb = *(const bf16x8*)&kb[16 * nt + l15][quad * 8 + ks * 32];
            wt[nt] = __builtin_amdgcn_mfma_f32_16x16x32_bf16(a, bb, wt[nt], 0, 0, 0);
        }
        if (w >= 4) {
            #pragma unroll
            for (int nt = 4; nt < 8; nt++) {
                bf16x8 bb = *(const bf16x8*)&kb[16 * nt + l15][quad * 8 + ks * 32];
                wt[nt] = __builtin_amdgcn_mfma_f32_16x16x32_bf16(a, bb, wt[nt], 0, 0, 0);
            }
        }
    }
    __syncthreads();   // all waves done reading qb/kb -> safe to overwrite with W

    // mask, round to bf16, rowsum (of rounded values!), store W:
    //   s < 64 -> kb region (Wlo),  s >= 64 -> qb region (Whi, waves 4-7 only)
    {
        const int tbase = 16 * w + quad * 4;               // chunk-local t of reg r=0
        float rsum[4] = {0.f, 0.f, 0.f, 0.f};
        #pragma unroll
        for (int nt = 0; nt < 4; nt++) {
            const int s = 16 * nt + l15;
            #pragma unroll
            for (int r = 0; r < 4; r++) {
                float val = (s > tbase + r) ? 0.f : wt[nt][r];
                unsigned short wb16 = f2b(val);
                kb[tbase + r][s] = wb16;
                rsum[r] += b2f(wb16);
            }
        }
        if (w >= 4) {
            #pragma unroll
            for (int nt = 4; nt < 8; nt++) {
                const int s = 16 * nt + l15;
                #pragma unroll
                for (int r = 0; r < 4; r++) {
                    float val = (s > tbase + r) ? 0.f : wt[nt][r];
                    unsigned short wb16 = f2b(val);
                    qb[tbase + r][s - 64] = wb16;
                    rsum[r] += b2f(wb16);
                }
            }
        }
        #pragma unroll
        for (int r = 0; r < 4; r++) {
            float rs = rsum[r];
            rs += __shfl_xor(rs, 8, 16);
            rs += __shfl_xor(rs, 4, 16);
            rs += __shfl_xor(rs, 2, 16);
            rs += __shfl_xor(rs, 1, 16);
            if (l15 == 0) den[tbase + r] += rs;
        }
    }
    __syncthreads();   // W + den visible

    // GEMM3: acc[t][e] += W[t][s] * V[s][e].  Waves 0-3 skip s>=64 (W is zero).
    #pragma unroll
    for (int ks = 0; ks < 2; ks++) {
        bf16x8 a = *(const bf16x8*)&kb[16 * w + l15][quad * 8 + ks * 32];
        #pragma unroll
        for (int nt = 0; nt < 4; nt++) {
            bf16x8 bb = *(const bf16x8*)&vb[swz(16 * nt + l15, quad * 8 + ks * 32)];
            acc[nt] = __builtin_amdgcn_mfma_f32_16x16x32_bf16(a, bb, acc[nt], 0, 0, 0);
        }
    }
    if (w >= 4) {
        #pragma unroll
        for (int ks = 2; ks < 4; ks++) {
            bf16x8 a = *(const bf16x8*)&qb[16 * w + l15][quad * 8 + (ks - 2) * 32];
            #pragma unroll
            for (int nt = 0; nt < 4; nt++) {
                bf16x8 bb = *(const bf16x8*)&vb[swz(16 * nt + l15, quad * 8 + ks * 32)];
                acc[nt] = __builtin_amdgcn_mfma_f32_16x16x32_bf16(a, bb, acc[nt], 0, 0, 0);
            }
        }
    }

    // epilogue: out[t][e] = acc / den[t]
    #pragma unroll
    for (int r = 0; r < 4; r++) {
        const int t = 16 * w + quad * 4 + r;
        const float inv = 1.0f / den[t];
        const size_t gbase = ((((size_t)b * Tc) + (t0 + t)) * Hc + h) * Dc;
        #pragma unroll
        for (int nt = 0; nt < 4; nt++) {
            outp[gbase + 16 * nt + l15] = acc[nt][r] * inv;
        }
    }
}

extern "C" void kernel_launch(void* const* d_in, const int* in_sizes, int n_in,
                              void* d_out, int out_size, void* d_ws, size_t ws_size,
                              hipStream_t stream) {
    const float* q = (const float*)d_in[0];
    const float* k = (const float*)d_in[1];
    const float* v = (const float*)d_in[2];
    float* out = (float*)d_out;
    float* ws  = (float*)d_ws;   // 4096*4160*4 = 68.2 MB

    k_chunkscan<<<BHc * SEG, 256, 0, stream>>>(k, v, ws);
    k_output<<<BHc * NCH, 512, 0, stream>>>(q, k, v, ws, out);
}

// Round 14
// 513.318 us; speedup vs baseline: 1.0489x; 1.0489x over previous
//
#include <hip/hip_runtime.h>
#include <hip/hip_bf16.h>

// Causal linear attention (ELU+1), chunked 3-pass, bf16 MFMA formulation.
// B=4, T=8192, H=16, D=64, fp32 in/out.
// ws: 4096 records (bh*NCH+c) of REC=4160 fp32: S^T[e][d] (4096) then z[d] (64).
//
// R14 vs R13 (538, regression) / R7 (507, best):
//  - R13's inline segment-base sum REVERTED: k_segscan restored (measured cost
//    only ~22 us; the inline sum cost k_output +53 us).
//  - k_output LDS 64.5 -> 48.75 KB => 3 blocks/CU (was 2, LDS-capped):
//    * pads replaced by XOR swizzles (stride 64/128; b128 reads <=2-way);
//    * sb UNIONed with vb: V^T held in 8 VGPRs from kernel-start loads
//      (T14 async-split), written over the dead sb region after the GEMM2
//      barrier (sb's last read is GEMM1, before that barrier).
//    Barrier count unchanged. Numerics bit-identical to R7.

#define EPS_ 1e-6f

constexpr int Bc  = 4;
constexpr int Tc  = 8192;
constexpr int Hc  = 16;
constexpr int Dc  = 64;
constexpr int CH  = 128;          // chunk length
constexpr int NCH = Tc / CH;      // 64
constexpr int BHc = Bc * Hc;      // 64
constexpr int REC = Dc * Dc + Dc; // 4160
constexpr int SEG = 16;           // segments per bh
constexpr int CPS = NCH / SEG;    // 4 chunks per segment

typedef short  bf16x8 __attribute__((ext_vector_type(8)));  // 8 bf16 (4 VGPRs)
typedef float  f32x4  __attribute__((ext_vector_type(4)));

__device__ __forceinline__ float phi_f(float x) {
    return x > 0.f ? x + 1.f : __expf(x);   // elu(x)+1
}
__device__ __forceinline__ unsigned short f2b(float x) {
    __hip_bfloat16 b = __float2bfloat16(x);          // round-to-nearest-even
    return __builtin_bit_cast(unsigned short, b);
}
__device__ __forceinline__ float b2f(unsigned short u) {
    return __uint_as_float(((unsigned)u) << 16);     // exact
}
// chunkscan tiles: [64][136] with 16B-block XOR (unchanged from R7).
__device__ __forceinline__ int swz136(int row, int colu) {
    return row * 136 + (colu ^ (((row >> 2) & 7) << 3));
}
// k_output tiles, stride 64 ushorts: XOR bits 3-5 with row&7.  b128 reads of
// 16 consecutive rows -> <=2-way; ushort4 writes stay contiguous (col%8 in
// {0,4} blocks move whole).  Staging writes ~8-way conflicted — tolerated
// (R7 proved these conflicts are off the critical path).
__device__ __forceinline__ int swz64(int row, int colu) {
    return row * 64 + (colu ^ ((row & 7) << 3));
}
// stride 128 ushorts (vb): XOR bits 3-6 with row&15 -> reads conflict-free.
__device__ __forceinline__ int swz128(int row, int colu) {
    return row * 128 + (colu ^ ((row & 15) << 3));
}

// ---- pass 1: segmented scan (unchanged from R7, measured 507-config) -------
__global__ __launch_bounds__(256, 4) void k_chunkscan(const float* __restrict__ kin,
                                                      const float* __restrict__ vin,
                                                      float* __restrict__ ws) {
    const int blk = blockIdx.x;              // bh*SEG + seg
    const int bh  = blk >> 4, seg = blk & (SEG - 1);
    const int b   = bh >> 4,  h   = bh & 15;
    const int tid = threadIdx.x;
    const int w = tid >> 6, lane = tid & 63;
    const int l15 = lane & 15, quad = lane >> 4;

    __shared__ unsigned short ktr[64 * 136];  // phiK^T [d][s] (swizzled)
    __shared__ unsigned short vtr[64 * 136];  // V^T    [e][s] (swizzled)
    __shared__ float zred[16][68];            // z partials (padded)

    const int c0 = (tid & 15) << 2;          // d/e col group 0..60
    const int rl = (tid >> 4) << 2;          // row group 0..60

    f32x4 acc[4];
    #pragma unroll
    for (int nt = 0; nt < 4; nt++) acc[nt] = (f32x4){0.f, 0.f, 0.f, 0.f};
    float zrun = 0.f;

    unsigned short hk[2][4][4], hv[2][4][4];
    float zp[4];

    auto load_chunk = [&](int c) {
        zp[0] = zp[1] = zp[2] = zp[3] = 0.f;
        #pragma unroll
        for (int sh = 0; sh < 2; ++sh) {
            const int r0 = rl + sh * 64;
            #pragma unroll
            for (int jj = 0; jj < 4; ++jj) {
                const size_t g = ((((size_t)b * Tc) + (c * CH + r0 + jj)) * Hc + h) * Dc + c0;
                const float4 kk = *(const float4*)(kin + g);
                const float4 vv = *(const float4*)(vin + g);
                hk[sh][jj][0] = f2b(phi_f(kk.x)); hk[sh][jj][1] = f2b(phi_f(kk.y));
                hk[sh][jj][2] = f2b(phi_f(kk.z)); hk[sh][jj][3] = f2b(phi_f(kk.w));
                hv[sh][jj][0] = f2b(vv.x); hv[sh][jj][1] = f2b(vv.y);
                hv[sh][jj][2] = f2b(vv.z); hv[sh][jj][3] = f2b(vv.w);
                #pragma unroll
                for (int j = 0; j < 4; ++j) zp[j] += b2f(hk[sh][jj][j]);
            }
        }
    };

    load_chunk(seg * CPS);

    for (int i = 0; i < CPS; ++i) {
        const int c = seg * CPS + i;
        float* rec = ws + (size_t)(bh * NCH + c) * REC;

        __syncthreads();

        #pragma unroll
        for (int sh = 0; sh < 2; ++sh) {
            const int r0 = rl + sh * 64;
            #pragma unroll
            for (int j = 0; j < 4; ++j) {
                *(ushort4*)&ktr[swz136(c0 + j, r0)] =
                    make_ushort4(hk[sh][0][j], hk[sh][1][j], hk[sh][2][j], hk[sh][3][j]);
                *(ushort4*)&vtr[swz136(c0 + j, r0)] =
                    make_ushort4(hv[sh][0][j], hv[sh][1][j], hv[sh][2][j], hv[sh][3][j]);
            }
        }
        #pragma unroll
        for (int j = 0; j < 4; ++j) zred[tid >> 4][c0 + j] = zp[j];

        if (i > 0) {
            #pragma unroll
            for (int nt = 0; nt < 4; nt++)
                #pragma unroll
                for (int r = 0; r < 4; r++)
                    rec[(16 * w + quad * 4 + r) * 64 + 16 * nt + l15] = acc[nt][r];
        }
        __syncthreads();

        float zs = 0.f;
        if (tid < 64) {
            if (i > 0) rec[4096 + tid] = zrun;
            #pragma unroll
            for (int g = 0; g < 16; g++) zs += zred[g][tid];
        }

        if (i + 1 < CPS) load_chunk(c + 1);

        #pragma unroll
        for (int ks = 0; ks < 4; ks++) {
            bf16x8 a = *(const bf16x8*)&vtr[swz136(16 * w + l15, quad * 8 + ks * 32)];
            #pragma unroll
            for (int nt = 0; nt < 4; nt++) {
                bf16x8 bb = *(const bf16x8*)&ktr[swz136(16 * nt + l15, quad * 8 + ks * 32)];
                acc[nt] = __builtin_amdgcn_mfma_f32_16x16x32_bf16(a, bb, acc[nt], 0, 0, 0);
            }
        }
        if (tid < 64) zrun += zs;
    }

    {
        float* rec0 = ws + (size_t)(bh * NCH + seg * CPS) * REC;
        #pragma unroll
        for (int nt = 0; nt < 4; nt++)
            #pragma unroll
            for (int r = 0; r < 4; r++)
                rec0[(16 * w + quad * 4 + r) * 64 + 16 * nt + l15] = acc[nt][r];
        if (tid < 64) rec0[4096 + tid] = zrun;
    }
}

// ---- pass 2: exclusive scan over SEG segment totals per bh (restored) ------
__global__ __launch_bounds__(256) void k_segscan(float* __restrict__ ws) {
    const int bh = blockIdx.x;
    const int e  = blockIdx.y * 256 + threadIdx.x;
    if (e >= REC) return;
    float* p = ws + (size_t)bh * NCH * REC + e;
    float t[SEG];
    #pragma unroll
    for (int s = 0; s < SEG; ++s) t[s] = p[(size_t)(s * CPS) * REC];
    float run = 0.f;
    #pragma unroll
    for (int s = 0; s < SEG; ++s) { p[(size_t)(s * CPS) * REC] = run; run += t[s]; }
}

// ---- pass 3: outputs.  LDS 48.75 KB -> 3 blocks/CU ------------------------
__global__ __launch_bounds__(512, 6) void k_output(const float* __restrict__ qin,
                                                   const float* __restrict__ kin,
                                                   const float* __restrict__ vin,
                                                   const float* __restrict__ ws,
                                                   float* __restrict__ outp) {
    const int chunk = blockIdx.x;                // bh*NCH + c
    const int bh = chunk >> 6, c = chunk & (NCH - 1);
    const int b = bh >> 4, h = bh & 15;
    const int t0 = c * CH;
    const int tid = threadIdx.x;
    const int w = tid >> 6, lane = tid & 63;
    const int l15 = lane & 15, quad = lane >> 4;

    __shared__ unsigned short qb[128 * 64];  // phiQ (swz64); later W[t][64+s']
    __shared__ unsigned short kb[128 * 64];  // phiK (swz64); later W[t][s<64]
    __shared__ unsigned short ub[64 * 128];  // UNION: sb (swz64, first 8KB) then vb (swz128)
    __shared__ float zsh[64];
    __shared__ float den[128];

    // ---- stage phi(q), phi(k) -> LDS; V -> registers (written later) ------
    {
        const int row = tid >> 2, cb = (tid & 3) << 4;
        const size_t g = ((((size_t)b * Tc) + (t0 + row)) * Hc + h) * Dc + cb;
        const float4* qp = (const float4*)(qin + g);
        const float4* kp = (const float4*)(kin + g);
        #pragma unroll
        for (int i = 0; i < 4; i++) {
            float4 qq = qp[i];
            float4 kk = kp[i];
            *(ushort4*)&qb[swz64(row, cb + 4 * i)] =
                make_ushort4(f2b(phi_f(qq.x)), f2b(phi_f(qq.y)), f2b(phi_f(qq.z)), f2b(phi_f(qq.w)));
            *(ushort4*)&kb[swz64(row, cb + 4 * i)] =
                make_ushort4(f2b(phi_f(kk.x)), f2b(phi_f(kk.y)), f2b(phi_f(kk.z)), f2b(phi_f(kk.w)));
        }
    }
    // V^T 4x4 in-register transpose, HELD in regs until after GEMM2 barrier
    unsigned short hv[4][4];
    const int vc0 = (tid & 15) << 2;             // e-col group 0..60
    const int vr0 = (tid >> 4) << 2;             // s-row group 0..124
    {
        #pragma unroll
        for (int jj = 0; jj < 4; ++jj) {
            const size_t g = ((((size_t)b * Tc) + (t0 + vr0 + jj)) * Hc + h) * Dc + vc0;
            const float4 vv = *(const float4*)(vin + g);
            hv[jj][0] = f2b(vv.x); hv[jj][1] = f2b(vv.y);
            hv[jj][2] = f2b(vv.z); hv[jj][3] = f2b(vv.w);
        }
    }
    // ---- stage (local prefix + segment base) -> sb region of ub, z -> zsh --
    {
        const float* rec = ws + (size_t)chunk * REC;
        const float* bse = ws + (size_t)(bh * NCH + (c & ~(CPS - 1))) * REC;
        const bool cz = ((c & (CPS - 1)) == 0);   // this record IS the base slot
        #pragma unroll
        for (int i = 0; i < 2; i++) {
            const int idx = tid + i * 512;       // float4 index, 0..1023
            float4 sv = ((const float4*)rec)[idx];
            float4 bv = ((const float4*)bse)[idx];
            float4 t;
            if (cz) t = bv;
            else { t.x = sv.x + bv.x; t.y = sv.y + bv.y; t.z = sv.z + bv.z; t.w = sv.w + bv.w; }
            const int flat = idx * 4, e = flat >> 6, d = flat & 63;
            *(ushort4*)&ub[swz64(e, d)] = make_ushort4(f2b(t.x), f2b(t.y), f2b(t.z), f2b(t.w));
        }
        if (tid < 16) {
            float4 zv = ((const float4*)(rec + 4096))[tid];
            float4 bz = ((const float4*)(bse + 4096))[tid];
            float4 t;
            if (cz) t = bz;
            else { t.x = zv.x + bz.x; t.y = zv.y + bz.y; t.z = zv.z + bz.z; t.w = zv.w + bz.w; }
            zsh[tid * 4 + 0] = t.x; zsh[tid * 4 + 1] = t.y;
            zsh[tid * 4 + 2] = t.z; zsh[tid * 4 + 3] = t.w;
        }
    }
    __syncthreads();

    // den0 = eps + phiQ[t] . z
    if (tid < 128) {
        float s = 0.f;
        #pragma unroll
        for (int j = 0; j < 8; j++) {
            bf16x8 qv = *(const bf16x8*)&qb[swz64(tid, j * 8)];
            #pragma unroll
            for (int u = 0; u < 8; u++) s += b2f((unsigned short)qv[u]) * zsh[j * 8 + u];
        }
        den[tid] = s + EPS_;
    }

    // GEMM1: acc[t][e] = phiQ[t][d] * S[d][e]   (B from sb rows in ub)
    f32x4 acc[4];
    #pragma unroll
    for (int nt = 0; nt < 4; nt++) acc[nt] = (f32x4){0.f, 0.f, 0.f, 0.f};
    #pragma unroll
    for (int ks = 0; ks < 2; ks++) {
        bf16x8 a = *(const bf16x8*)&qb[swz64(16 * w + l15, quad * 8 + ks * 32)];
        #pragma unroll
        for (int nt = 0; nt < 4; nt++) {
            bf16x8 bb = *(const bf16x8*)&ub[swz64(16 * nt + l15, quad * 8 + ks * 32)];
            acc[nt] = __builtin_amdgcn_mfma_f32_16x16x32_bf16(a, bb, acc[nt], 0, 0, 0);
        }
    }

    // GEMM2: W[t][s] = phiQ[t][d] * phiK[s][d].  Waves 0-3 skip s>=64.
    f32x4 wt[8];
    #pragma unroll
    for (int nt = 0; nt < 8; nt++) wt[nt] = (f32x4){0.f, 0.f, 0.f, 0.f};
    #pragma unroll
    for (int ks = 0; ks < 2; ks++) {
        bf16x8 a = *(const bf16x8*)&qb[swz64(16 * w + l15, quad * 8 + ks * 32)];
        #pragma unroll
        for (int nt = 0; nt < 4; nt++) {
            bf16x8 bb = *(const bf16x8*)&kb[swz64(16 * nt + l15, quad * 8 + ks * 32)];
            wt[nt] = __builtin_amdgcn_mfma_f32_16x16x32_bf16(a, bb, wt[nt], 0, 0, 0);
        }
        if (w >= 4) {
            #pragma unroll
            for (int nt = 4; nt < 8; nt++) {
                bf16x8 bb = *(const bf16x8*)&kb[swz64(16 * nt + l15, quad * 8 + ks * 32)];
                wt[nt] = __builtin_amdgcn_mfma_f32_16x16x32_bf16(a, bb, wt[nt], 0, 0, 0);
            }
        }
    }
    __syncthreads();   // GEMM1 done with sb (ub) -> vb write OK; qb/kb -> W OK

    // write V^T (held regs) into ub as vb (swz128)
    {
        #pragma unroll
        for (int j = 0; j < 4; ++j)
            *(ushort4*)&ub[swz128(vc0 + j, vr0)] =
                make_ushort4(hv[0][j], hv[1][j], hv[2][j], hv[3][j]);
    }
    // mask, round to bf16, rowsum of rounded values, store W into kb/qb
    {
        const int tbase = 16 * w + quad * 4;
        float rsum[4] = {0.f, 0.f, 0.f, 0.f};
        #pragma unroll
        for (int nt = 0; nt < 4; nt++) {
            const int s = 16 * nt + l15;
            #pragma unroll
            for (int r = 0; r < 4; r++) {
                float val = (s > tbase + r) ? 0.f : wt[nt][r];
                unsigned short wb16 = f2b(val);
                kb[swz64(tbase + r, s)] = wb16;
                rsum[r] += b2f(wb16);
            }
        }
        if (w >= 4) {
            #pragma unroll
            for (int nt = 4; nt < 8; nt++) {
                const int s = 16 * nt + l15;
                #pragma unroll
                for (int r = 0; r < 4; r++) {
                    float val = (s > tbase + r) ? 0.f : wt[nt][r];
                    unsigned short wb16 = f2b(val);
                    qb[swz64(tbase + r, s - 64)] = wb16;
                    rsum[r] += b2f(wb16);
                }
            }
        }
        #pragma unroll
        for (int r = 0; r < 4; r++) {
            float rs = rsum[r];
            rs += __shfl_xor(rs, 8, 16);
            rs += __shfl_xor(rs, 4, 16);
            rs += __shfl_xor(rs, 2, 16);
            rs += __shfl_xor(rs, 1, 16);
            if (l15 == 0) den[tbase + r] += rs;
        }
    }
    __syncthreads();   // vb + W + den visible

    // GEMM3: acc[t][e] += W[t][s] * V[s][e]
    #pragma unroll
    for (int ks = 0; ks < 2; ks++) {
        bf16x8 a = *(const bf16x8*)&kb[swz64(16 * w + l15, quad * 8 + ks * 32)];
        #pragma unroll
        for (int nt = 0; nt < 4; nt++) {
            bf16x8 bb = *(const bf16x8*)&ub[swz128(16 * nt + l15, quad * 8 + ks * 32)];
            acc[nt] = __builtin_amdgcn_mfma_f32_16x16x32_bf16(a, bb, acc[nt], 0, 0, 0);
        }
    }
    if (w >= 4) {
        #pragma unroll
        for (int ks = 2; ks < 4; ks++) {
            bf16x8 a = *(const bf16x8*)&qb[swz64(16 * w + l15, quad * 8 + (ks - 2) * 32)];
            #pragma unroll
            for (int nt = 0; nt < 4; nt++) {
                bf16x8 bb = *(const bf16x8*)&ub[swz128(16 * nt + l15, quad * 8 + ks * 32)];
                acc[nt] = __builtin_amdgcn_mfma_f32_16x16x32_bf16(a, bb, acc[nt], 0, 0, 0);
            }
        }
    }

    // epilogue: out[t][e] = acc / den[t]
    #pragma unroll
    for (int r = 0; r < 4; r++) {
        const int t = 16 * w + quad * 4 + r;
        const float inv = 1.0f / den[t];
        const size_t gbase = ((((size_t)b * Tc) + (t0 + t)) * Hc + h) * Dc;
        #pragma unroll
        for (int nt = 0; nt < 4; nt++) {
            outp[gbase + 16 * nt + l15] = acc[nt][r] * inv;
        }
    }
}

extern "C" void kernel_launch(void* const* d_in, const int* in_sizes, int n_in,
                              void* d_out, int out_size, void* d_ws, size_t ws_size,
                              hipStream_t stream) {
    const float* q = (const float*)d_in[0];
    const float* k = (const float*)d_in[1];
    const float* v = (const float*)d_in[2];
    float* out = (float*)d_out;
    float* ws  = (float*)d_ws;   // 4096*4160*4 = 68.2 MB

    k_chunkscan<<<BHc * SEG, 256, 0, stream>>>(k, v, ws);
    dim3 g2(BHc, (REC + 255) / 256);
    k_segscan<<<g2, 256, 0, stream>>>(ws);
    k_output<<<BHc * NCH, 512, 0, stream>>>(q, k, v, ws, out);
}

// Round 15
// 491.917 us; speedup vs baseline: 1.0946x; 1.0435x over previous
//
#include <hip/hip_runtime.h>
#include <hip/hip_bf16.h>

// Causal linear attention (ELU+1), chunked 3-pass, bf16 MFMA formulation.
// B=4, T=8192, H=16, D=64, fp32 in/out.
// ws: 4096 records (bh*NCH+c) of REC=4160 fp32: S^T[e][d] (4096) then z[d] (64).
//
// R15 vs R14 (513; k_output 150us, spill: WRITE +74MB, VGPR 52->40):
//  - V is NOT held in registers across GEMM1/GEMM2 (that spilled to scratch).
//    Instead V is loaded from global AFTER the GEMM2 barrier (sb region of ub
//    is dead there) and written straight into ub (swz128).  V still read
//    exactly once; no long-lived regs -> no scratch traffic.
//  - Everything else identical to R14: 48.75 KB LDS -> 3 blocks/CU,
//    XOR-swizzled tiles, sb/vb union, R7 chunkscan + segscan.
//  Numerics bit-identical to R7/R14 (absmax 0.015625).

#define EPS_ 1e-6f

constexpr int Bc  = 4;
constexpr int Tc  = 8192;
constexpr int Hc  = 16;
constexpr int Dc  = 64;
constexpr int CH  = 128;          // chunk length
constexpr int NCH = Tc / CH;      // 64
constexpr int BHc = Bc * Hc;      // 64
constexpr int REC = Dc * Dc + Dc; // 4160
constexpr int SEG = 16;           // segments per bh
constexpr int CPS = NCH / SEG;    // 4 chunks per segment

typedef short  bf16x8 __attribute__((ext_vector_type(8)));  // 8 bf16 (4 VGPRs)
typedef float  f32x4  __attribute__((ext_vector_type(4)));

__device__ __forceinline__ float phi_f(float x) {
    return x > 0.f ? x + 1.f : __expf(x);   // elu(x)+1
}
__device__ __forceinline__ unsigned short f2b(float x) {
    __hip_bfloat16 b = __float2bfloat16(x);          // round-to-nearest-even
    return __builtin_bit_cast(unsigned short, b);
}
__device__ __forceinline__ float b2f(unsigned short u) {
    return __uint_as_float(((unsigned)u) << 16);     // exact
}
// chunkscan tiles: [64][136] with 16B-block XOR (unchanged from R7).
__device__ __forceinline__ int swz136(int row, int colu) {
    return row * 136 + (colu ^ (((row >> 2) & 7) << 3));
}
// k_output tiles, stride 64 ushorts: XOR bits 3-5 with row&7.  b128 reads of
// 16 consecutive rows -> <=2-way; ushort4 writes stay contiguous.
__device__ __forceinline__ int swz64(int row, int colu) {
    return row * 64 + (colu ^ ((row & 7) << 3));
}
// stride 128 ushorts (vb): XOR bits 3-6 with row&15 -> b128 reads <=2-way.
__device__ __forceinline__ int swz128(int row, int colu) {
    return row * 128 + (colu ^ ((row & 15) << 3));
}

// ---- pass 1: segmented scan (unchanged from R7, measured 507-config) -------
__global__ __launch_bounds__(256, 4) void k_chunkscan(const float* __restrict__ kin,
                                                      const float* __restrict__ vin,
                                                      float* __restrict__ ws) {
    const int blk = blockIdx.x;              // bh*SEG + seg
    const int bh  = blk >> 4, seg = blk & (SEG - 1);
    const int b   = bh >> 4,  h   = bh & 15;
    const int tid = threadIdx.x;
    const int w = tid >> 6, lane = tid & 63;
    const int l15 = lane & 15, quad = lane >> 4;

    __shared__ unsigned short ktr[64 * 136];  // phiK^T [d][s] (swizzled)
    __shared__ unsigned short vtr[64 * 136];  // V^T    [e][s] (swizzled)
    __shared__ float zred[16][68];            // z partials (padded)

    const int c0 = (tid & 15) << 2;          // d/e col group 0..60
    const int rl = (tid >> 4) << 2;          // row group 0..60

    f32x4 acc[4];
    #pragma unroll
    for (int nt = 0; nt < 4; nt++) acc[nt] = (f32x4){0.f, 0.f, 0.f, 0.f};
    float zrun = 0.f;

    unsigned short hk[2][4][4], hv[2][4][4];
    float zp[4];

    auto load_chunk = [&](int c) {
        zp[0] = zp[1] = zp[2] = zp[3] = 0.f;
        #pragma unroll
        for (int sh = 0; sh < 2; ++sh) {
            const int r0 = rl + sh * 64;
            #pragma unroll
            for (int jj = 0; jj < 4; ++jj) {
                const size_t g = ((((size_t)b * Tc) + (c * CH + r0 + jj)) * Hc + h) * Dc + c0;
                const float4 kk = *(const float4*)(kin + g);
                const float4 vv = *(const float4*)(vin + g);
                hk[sh][jj][0] = f2b(phi_f(kk.x)); hk[sh][jj][1] = f2b(phi_f(kk.y));
                hk[sh][jj][2] = f2b(phi_f(kk.z)); hk[sh][jj][3] = f2b(phi_f(kk.w));
                hv[sh][jj][0] = f2b(vv.x); hv[sh][jj][1] = f2b(vv.y);
                hv[sh][jj][2] = f2b(vv.z); hv[sh][jj][3] = f2b(vv.w);
                #pragma unroll
                for (int j = 0; j < 4; ++j) zp[j] += b2f(hk[sh][jj][j]);
            }
        }
    };

    load_chunk(seg * CPS);

    for (int i = 0; i < CPS; ++i) {
        const int c = seg * CPS + i;
        float* rec = ws + (size_t)(bh * NCH + c) * REC;

        __syncthreads();

        #pragma unroll
        for (int sh = 0; sh < 2; ++sh) {
            const int r0 = rl + sh * 64;
            #pragma unroll
            for (int j = 0; j < 4; ++j) {
                *(ushort4*)&ktr[swz136(c0 + j, r0)] =
                    make_ushort4(hk[sh][0][j], hk[sh][1][j], hk[sh][2][j], hk[sh][3][j]);
                *(ushort4*)&vtr[swz136(c0 + j, r0)] =
                    make_ushort4(hv[sh][0][j], hv[sh][1][j], hv[sh][2][j], hv[sh][3][j]);
            }
        }
        #pragma unroll
        for (int j = 0; j < 4; ++j) zred[tid >> 4][c0 + j] = zp[j];

        if (i > 0) {
            #pragma unroll
            for (int nt = 0; nt < 4; nt++)
                #pragma unroll
                for (int r = 0; r < 4; r++)
                    rec[(16 * w + quad * 4 + r) * 64 + 16 * nt + l15] = acc[nt][r];
        }
        __syncthreads();

        float zs = 0.f;
        if (tid < 64) {
            if (i > 0) rec[4096 + tid] = zrun;
            #pragma unroll
            for (int g = 0; g < 16; g++) zs += zred[g][tid];
        }

        if (i + 1 < CPS) load_chunk(c + 1);

        #pragma unroll
        for (int ks = 0; ks < 4; ks++) {
            bf16x8 a = *(const bf16x8*)&vtr[swz136(16 * w + l15, quad * 8 + ks * 32)];
            #pragma unroll
            for (int nt = 0; nt < 4; nt++) {
                bf16x8 bb = *(const bf16x8*)&ktr[swz136(16 * nt + l15, quad * 8 + ks * 32)];
                acc[nt] = __builtin_amdgcn_mfma_f32_16x16x32_bf16(a, bb, acc[nt], 0, 0, 0);
            }
        }
        if (tid < 64) zrun += zs;
    }

    {
        float* rec0 = ws + (size_t)(bh * NCH + seg * CPS) * REC;
        #pragma unroll
        for (int nt = 0; nt < 4; nt++)
            #pragma unroll
            for (int r = 0; r < 4; r++)
                rec0[(16 * w + quad * 4 + r) * 64 + 16 * nt + l15] = acc[nt][r];
        if (tid < 64) rec0[4096 + tid] = zrun;
    }
}

// ---- pass 2: exclusive scan over SEG segment totals per bh -----------------
__global__ __launch_bounds__(256) void k_segscan(float* __restrict__ ws) {
    const int bh = blockIdx.x;
    const int e  = blockIdx.y * 256 + threadIdx.x;
    if (e >= REC) return;
    float* p = ws + (size_t)bh * NCH * REC + e;
    float t[SEG];
    #pragma unroll
    for (int s = 0; s < SEG; ++s) t[s] = p[(size_t)(s * CPS) * REC];
    float run = 0.f;
    #pragma unroll
    for (int s = 0; s < SEG; ++s) { p[(size_t)(s * CPS) * REC] = run; run += t[s]; }
}

// ---- pass 3: outputs.  48.75 KB LDS -> 3 blocks/CU; V loaded post-GEMM2 ----
__global__ __launch_bounds__(512, 6) void k_output(const float* __restrict__ qin,
                                                   const float* __restrict__ kin,
                                                   const float* __restrict__ vin,
                                                   const float* __restrict__ ws,
                                                   float* __restrict__ outp) {
    const int chunk = blockIdx.x;                // bh*NCH + c
    const int bh = chunk >> 6, c = chunk & (NCH - 1);
    const int b = bh >> 4, h = bh & 15;
    const int t0 = c * CH;
    const int tid = threadIdx.x;
    const int w = tid >> 6, lane = tid & 63;
    const int l15 = lane & 15, quad = lane >> 4;

    __shared__ unsigned short qb[128 * 64];  // phiQ (swz64); later W[t][64+s']
    __shared__ unsigned short kb[128 * 64];  // phiK (swz64); later W[t][s<64]
    __shared__ unsigned short ub[64 * 128];  // UNION: sb (swz64) then vb (swz128)
    __shared__ float zsh[64];
    __shared__ float den[128];

    // ---- stage phi(q), phi(k) -> LDS --------------------------------------
    {
        const int row = tid >> 2, cb = (tid & 3) << 4;
        const size_t g = ((((size_t)b * Tc) + (t0 + row)) * Hc + h) * Dc + cb;
        const float4* qp = (const float4*)(qin + g);
        const float4* kp = (const float4*)(kin + g);
        #pragma unroll
        for (int i = 0; i < 4; i++) {
            float4 qq = qp[i];
            float4 kk = kp[i];
            *(ushort4*)&qb[swz64(row, cb + 4 * i)] =
                make_ushort4(f2b(phi_f(qq.x)), f2b(phi_f(qq.y)), f2b(phi_f(qq.z)), f2b(phi_f(qq.w)));
            *(ushort4*)&kb[swz64(row, cb + 4 * i)] =
                make_ushort4(f2b(phi_f(kk.x)), f2b(phi_f(kk.y)), f2b(phi_f(kk.z)), f2b(phi_f(kk.w)));
        }
    }
    // ---- stage (local prefix + segment base) -> sb region of ub, z -> zsh --
    {
        const float* rec = ws + (size_t)chunk * REC;
        const float* bse = ws + (size_t)(bh * NCH + (c & ~(CPS - 1))) * REC;
        const bool cz = ((c & (CPS - 1)) == 0);   // this record IS the base slot
        #pragma unroll
        for (int i = 0; i < 2; i++) {
            const int idx = tid + i * 512;       // float4 index, 0..1023
            float4 sv = ((const float4*)rec)[idx];
            float4 bv = ((const float4*)bse)[idx];
            float4 t;
            if (cz) t = bv;
            else { t.x = sv.x + bv.x; t.y = sv.y + bv.y; t.z = sv.z + bv.z; t.w = sv.w + bv.w; }
            const int flat = idx * 4, e = flat >> 6, d = flat & 63;
            *(ushort4*)&ub[swz64(e, d)] = make_ushort4(f2b(t.x), f2b(t.y), f2b(t.z), f2b(t.w));
        }
        if (tid < 16) {
            float4 zv = ((const float4*)(rec + 4096))[tid];
            float4 bz = ((const float4*)(bse + 4096))[tid];
            float4 t;
            if (cz) t = bz;
            else { t.x = zv.x + bz.x; t.y = zv.y + bz.y; t.z = zv.z + bz.z; t.w = zv.w + bz.w; }
            zsh[tid * 4 + 0] = t.x; zsh[tid * 4 + 1] = t.y;
            zsh[tid * 4 + 2] = t.z; zsh[tid * 4 + 3] = t.w;
        }
    }
    __syncthreads();

    // den0 = eps + phiQ[t] . z
    if (tid < 128) {
        float s = 0.f;
        #pragma unroll
        for (int j = 0; j < 8; j++) {
            bf16x8 qv = *(const bf16x8*)&qb[swz64(tid, j * 8)];
            #pragma unroll
            for (int u = 0; u < 8; u++) s += b2f((unsigned short)qv[u]) * zsh[j * 8 + u];
        }
        den[tid] = s + EPS_;
    }

    // GEMM1: acc[t][e] = phiQ[t][d] * S[d][e]   (B from sb rows in ub)
    f32x4 acc[4];
    #pragma unroll
    for (int nt = 0; nt < 4; nt++) acc[nt] = (f32x4){0.f, 0.f, 0.f, 0.f};
    #pragma unroll
    for (int ks = 0; ks < 2; ks++) {
        bf16x8 a = *(const bf16x8*)&qb[swz64(16 * w + l15, quad * 8 + ks * 32)];
        #pragma unroll
        for (int nt = 0; nt < 4; nt++) {
            bf16x8 bb = *(const bf16x8*)&ub[swz64(16 * nt + l15, quad * 8 + ks * 32)];
            acc[nt] = __builtin_amdgcn_mfma_f32_16x16x32_bf16(a, bb, acc[nt], 0, 0, 0);
        }
    }

    // GEMM2: W[t][s] = phiQ[t][d] * phiK[s][d].  Waves 0-3 skip s>=64.
    f32x4 wt[8];
    #pragma unroll
    for (int nt = 0; nt < 8; nt++) wt[nt] = (f32x4){0.f, 0.f, 0.f, 0.f};
    #pragma unroll
    for (int ks = 0; ks < 2; ks++) {
        bf16x8 a = *(const bf16x8*)&qb[swz64(16 * w + l15, quad * 8 + ks * 32)];
        #pragma unroll
        for (int nt = 0; nt < 4; nt++) {
            bf16x8 bb = *(const bf16x8*)&kb[swz64(16 * nt + l15, quad * 8 + ks * 32)];
            wt[nt] = __builtin_amdgcn_mfma_f32_16x16x32_bf16(a, bb, wt[nt], 0, 0, 0);
        }
        if (w >= 4) {
            #pragma unroll
            for (int nt = 4; nt < 8; nt++) {
                bf16x8 bb = *(const bf16x8*)&kb[swz64(16 * nt + l15, quad * 8 + ks * 32)];
                wt[nt] = __builtin_amdgcn_mfma_f32_16x16x32_bf16(a, bb, wt[nt], 0, 0, 0);
            }
        }
    }
    __syncthreads();   // GEMM1 done with sb (ub) -> V write OK; qb/kb -> W OK

    // load V from global NOW (sb dead), 4x4 in-register transpose -> ub (swz128).
    // Issued first so the HBM latency overlaps the W-store/rowsum VALU below.
    {
        const int vc0 = (tid & 15) << 2;         // e-col group 0..60
        const int vr0 = (tid >> 4) << 2;         // s-row group 0..124
        unsigned short hv[4][4];
        #pragma unroll
        for (int jj = 0; jj < 4; ++jj) {
            const size_t g = ((((size_t)b * Tc) + (t0 + vr0 + jj)) * Hc + h) * Dc + vc0;
            const float4 vv = *(const float4*)(vin + g);
            hv[jj][0] = f2b(vv.x); hv[jj][1] = f2b(vv.y);
            hv[jj][2] = f2b(vv.z); hv[jj][3] = f2b(vv.w);
        }
        #pragma unroll
        for (int j = 0; j < 4; ++j)
            *(ushort4*)&ub[swz128(vc0 + j, vr0)] =
                make_ushort4(hv[0][j], hv[1][j], hv[2][j], hv[3][j]);
    }
    // mask, round to bf16, rowsum of rounded values, store W into kb/qb
    {
        const int tbase = 16 * w + quad * 4;
        float rsum[4] = {0.f, 0.f, 0.f, 0.f};
        #pragma unroll
        for (int nt = 0; nt < 4; nt++) {
            const int s = 16 * nt + l15;
            #pragma unroll
            for (int r = 0; r < 4; r++) {
                float val = (s > tbase + r) ? 0.f : wt[nt][r];
                unsigned short wb16 = f2b(val);
                kb[swz64(tbase + r, s)] = wb16;
                rsum[r] += b2f(wb16);
            }
        }
        if (w >= 4) {
            #pragma unroll
            for (int nt = 4; nt < 8; nt++) {
                const int s = 16 * nt + l15;
                #pragma unroll
                for (int r = 0; r < 4; r++) {
                    float val = (s > tbase + r) ? 0.f : wt[nt][r];
                    unsigned short wb16 = f2b(val);
                    qb[swz64(tbase + r, s - 64)] = wb16;
                    rsum[r] += b2f(wb16);
                }
            }
        }
        #pragma unroll
        for (int r = 0; r < 4; r++) {
            float rs = rsum[r];
            rs += __shfl_xor(rs, 8, 16);
            rs += __shfl_xor(rs, 4, 16);
            rs += __shfl_xor(rs, 2, 16);
            rs += __shfl_xor(rs, 1, 16);
            if (l15 == 0) den[tbase + r] += rs;
        }
    }
    __syncthreads();   // vb + W + den visible

    // GEMM3: acc[t][e] += W[t][s] * V[s][e]
    #pragma unroll
    for (int ks = 0; ks < 2; ks++) {
        bf16x8 a = *(const bf16x8*)&kb[swz64(16 * w + l15, quad * 8 + ks * 32)];
        #pragma unroll
        for (int nt = 0; nt < 4; nt++) {
            bf16x8 bb = *(const bf16x8*)&ub[swz128(16 * nt + l15, quad * 8 + ks * 32)];
            acc[nt] = __builtin_amdgcn_mfma_f32_16x16x32_bf16(a, bb, acc[nt], 0, 0, 0);
        }
    }
    if (w >= 4) {
        #pragma unroll
        for (int ks = 2; ks < 4; ks++) {
            bf16x8 a = *(const bf16x8*)&qb[swz64(16 * w + l15, quad * 8 + (ks - 2) * 32)];
            #pragma unroll
            for (int nt = 0; nt < 4; nt++) {
                bf16x8 bb = *(const bf16x8*)&ub[swz128(16 * nt + l15, quad * 8 + ks * 32)];
                acc[nt] = __builtin_amdgcn_mfma_f32_16x16x32_bf16(a, bb, acc[nt], 0, 0, 0);
            }
        }
    }

    // epilogue: out[t][e] = acc / den[t]
    #pragma unroll
    for (int r = 0; r < 4; r++) {
        const int t = 16 * w + quad * 4 + r;
        const float inv = 1.0f / den[t];
        const size_t gbase = ((((size_t)b * Tc) + (t0 + t)) * Hc + h) * Dc;
        #pragma unroll
        for (int nt = 0; nt < 4; nt++) {
            outp[gbase + 16 * nt + l15] = acc[nt][r] * inv;
        }
    }
}

extern "C" void kernel_launch(void* const* d_in, const int* in_sizes, int n_in,
                              void* d_out, int out_size, void* d_ws, size_t ws_size,
                              hipStream_t stream) {
    const float* q = (const float*)d_in[0];
    const float* k = (const float*)d_in[1];
    const float* v = (const float*)d_in[2];
    float* out = (float*)d_out;
    float* ws  = (float*)d_ws;   // 4096*4160*4 = 68.2 MB

    k_chunkscan<<<BHc * SEG, 256, 0, stream>>>(k, v, ws);
    dim3 g2(BHc, (REC + 255) / 256);
    k_segscan<<<g2, 256, 0, stream>>>(ws);
    k_output<<<BHc * NCH, 512, 0, stream>>>(q, k, v, ws, out);
}